// Round 7
// baseline (903.804 us; speedup 1.0000x reference)
//
#include <hip/hip_runtime.h>
#include <hip/hip_cooperative_groups.h>
#include <hip/hip_bf16.h>

namespace cg = cooperative_groups;

#define NN   12288
#define EE   393216
#define BG   16
#define FIN  15
#define FH1  32
#define FH2  64
#define NCL  11
#define BNEPS 1e-5f
#define NB   256
#define NT   256
#define TT   (NB*NT)

struct Params {
  const float *x,*ea,*we,*bedg;
  const float *w1,*b1,*g1,*be1;
  const float *w2,*b2,*g2,*be2;
  const float *w3,*b3,*g3,*be3;
  const float *wf1,*bf1,*gf1,*bef1;
  const float *wf2,*bf2,*gf2,*bef2;
  const float *wf3,*bf3;
  const void *ei,*batch;
  float *out;
  float *deg,*dis,*csr_w,*P1,*P2,*P3,*cs1,*cs2,*cs3,*embf,*z1,*s1g,*z2,*s2g;
  int *cnt,*rowptr,*fillp,*csr_col,*bsum,*flags;
};

__device__ __forceinline__ int getIdx(const void* p, long i, int is64){
  return is64 ? (int)((const long long*)p)[i] : ((const int*)p)[i];
}

__global__ void __launch_bounds__(NT) mega(Params p){
  cg::grid_group grid = cg::this_grid();
  const int tid  = threadIdx.x;
  const int gtid = blockIdx.x*NT + tid;

  // ---- P0: init + int-width detect (wave 0 of block 0, ballot) ----
  if (gtid < NN){ p.deg[gtid]=1.0f; p.cnt[gtid]=0; }
  if (gtid < 384){ (gtid<128 ? p.cs1 : (gtid<256 ? p.cs2 : p.cs3))[gtid & 127] = 0.f; }
  if (gtid < BG*64) p.embf[gtid]=0.f;
  if (blockIdx.x==0 && tid<64){
    const int* a=(const int*)p.ei;
    unsigned long long m0 = __ballot(a[2*tid+1]==0);
    const int* b=(const int*)p.batch;
    int j=96*tid;
    unsigned long long m1 = __ballot(b[2*j+1]==0);
    if (tid==0){ p.flags[0] = (m0==~0ull) ? 1 : 0; p.flags[1] = (m1==~0ull) ? 1 : 0; }
  }
  grid.sync();

  const int is64  = p.flags[0];
  const int isb64 = p.flags[1];

  // ---- P1: edge pass 1 — weighted degree + row counts ----
  {
    float w0=p.we[0], w1v=p.we[1], b0=p.bedg[0];
    for (int e=gtid; e<EE; e+=TT){
      float z = p.ea[2*e]*w0 + p.ea[2*e+1]*w1v + b0;
      float w = 1.f/(1.f+expf(-z));
      int r = getIdx(p.ei, e, is64);
      atomicAdd(&p.deg[r], w);
      atomicAdd(&p.cnt[r], 1);
    }
  }
  grid.sync();

  // ---- P2a: per-chunk scan (48 blocks x 256) ----
  {
    __shared__ int sbuf[NT];
    if (blockIdx.x < 48){
      int i = blockIdx.x*NT + tid;
      int v = p.cnt[i];
      sbuf[tid]=v;
      __syncthreads();
      for (int off=1; off<NT; off<<=1){
        int add = (tid>=off)? sbuf[tid-off]:0;
        __syncthreads();
        sbuf[tid]+=add;
        __syncthreads();
      }
      p.rowptr[i] = sbuf[tid]-v;
      if (tid==NT-1) p.bsum[blockIdx.x]=sbuf[tid];
    }
  }
  grid.sync();

  // ---- P2b: scan the 48 block sums (block 0) ----
  {
    if (blockIdx.x==0){
      __shared__ int sb[64];
      int v=0;
      if (tid<64){ v=(tid<48)? p.bsum[tid]:0; sb[tid]=v; }
      __syncthreads();
      for (int off=1; off<64; off<<=1){
        int add=(tid<64 && tid>=off)? sb[tid-off]:0;
        __syncthreads();
        if (tid<64) sb[tid]+=add;
        __syncthreads();
      }
      if (tid<48) p.bsum[tid]=sb[tid]-v;
    }
  }
  grid.sync();

  // ---- P2c: add offsets, copy to fillp, dis=rsqrt(deg) ----
  if (gtid<NN){
    int rp = p.rowptr[gtid] + p.bsum[gtid>>8];
    p.rowptr[gtid]=rp;
    p.fillp[gtid]=rp;
    p.dis[gtid]=rsqrtf(p.deg[gtid]);
  }
  grid.sync();

  // ---- P3: edge pass 2 — fill CSR (col + w*dis[col]) ----
  {
    float w0=p.we[0], w1v=p.we[1], b0=p.bedg[0];
    for (int e=gtid; e<EE; e+=TT){
      int r=getIdx(p.ei,e,is64);
      int c=getIdx(p.ei,(long)EE+e,is64);
      float z=p.ea[2*e]*w0+p.ea[2*e+1]*w1v+b0;
      float w=1.f/(1.f+expf(-z));
      int slot=atomicAdd(&p.fillp[r],1);
      p.csr_col[slot]=c;
      p.csr_w[slot]=w*p.dis[c];
    }
  }
  grid.sync();

  // ---- P4: layer 1 — gather(x) + gemm(w1) + colsum -> P1, cs1 ----
  {
    __shared__ float At[48][FIN];
    int rb = blockIdx.x*48;
    int f = tid & 15, lrb = tid >> 4;
    for (int pass=0; pass<3; pass++){
      int lr = pass*16 + lrb, row = rb+lr;
      if (f < FIN){
        float d = p.dis[row];
        float acc = d * p.x[row*FIN+f];
        int beg=p.rowptr[row], n=p.cnt[row];
        for (int j=0;j<n;j++)
          acc += p.csr_w[beg+j] * p.x[(long)p.csr_col[beg+j]*FIN + f];
        At[lr][f] = d*acc;
      }
    }
    __syncthreads();
    int fo = tid & 31;
    float sa=0.f, qa=0.f;
    for (int o=tid; o<48*FH1; o+=NT){
      int lr=o>>5;
      float s=p.b1[fo];
      #pragma unroll
      for (int fi=0; fi<FIN; fi++) s += At[lr][fi]*p.w1[fi*FH1+fo];
      p.P1[(rb+lr)*FH1+fo]=s;
      sa+=s; qa+=s*s;
    }
    __shared__ float lcs[FH1], lcq[FH1];
    if (tid<FH1){ lcs[tid]=0.f; lcq[tid]=0.f; }
    __syncthreads();
    atomicAdd(&lcs[fo],sa); atomicAdd(&lcq[fo],qa);
    __syncthreads();
    if (tid<FH1){ atomicAdd(&p.cs1[tid],lcs[tid]); atomicAdd(&p.cs1[FH1+tid],lcq[tid]); }
  }
  grid.sync();

  // ---- P5: layer 2 — gather(BN1(P1)) + gemm(w2) + colsum -> P2, cs2 ----
  {
    __shared__ float At[48][FH1];
    int f = tid & 31, lrb = tid >> 5;
    float mu = p.cs1[f]*(1.f/NN);
    float var = p.cs1[FH1+f]*(1.f/NN) - mu*mu;
    float rinv = rsqrtf(var+BNEPS);
    float sc = p.g1[f]*rinv, sh = p.be1[f]-mu*sc;
    int rb = blockIdx.x*48;
    for (int pass=0; pass<6; pass++){
      int lr = pass*8 + lrb, row = rb+lr;
      float d=p.dis[row];
      float acc = d * fmaxf(p.P1[row*FH1+f]*sc+sh, 0.f);
      int beg=p.rowptr[row], n=p.cnt[row];
      for (int j=0;j<n;j++){
        int c=p.csr_col[beg+j];
        acc += p.csr_w[beg+j]*fmaxf(p.P1[c*FH1+f]*sc+sh,0.f);
      }
      At[lr][f]=d*acc;
    }
    __syncthreads();
    int fo = tid & 63;
    float sa=0.f, qa=0.f;
    for (int o=tid;o<48*FH2;o+=NT){
      int lr=o>>6;
      float s=p.b2[fo];
      #pragma unroll
      for (int fi=0;fi<FH1;fi++) s+=At[lr][fi]*p.w2[fi*FH2+fo];
      p.P2[(rb+lr)*FH2+fo]=s;
      sa+=s; qa+=s*s;
    }
    __shared__ float lcs[FH2], lcq[FH2];
    if (tid<FH2){lcs[tid]=0.f;lcq[tid]=0.f;}
    __syncthreads();
    atomicAdd(&lcs[fo],sa); atomicAdd(&lcq[fo],qa);
    __syncthreads();
    if (tid<FH2){atomicAdd(&p.cs2[tid],lcs[tid]); atomicAdd(&p.cs2[FH2+tid],lcq[tid]);}
  }
  grid.sync();

  // ---- P6: layer 3 — gather(BN2(P2)) + gemm(w3) + colsum -> P3, cs3 ----
  {
    __shared__ float At[48][FH2];
    int f=tid&63, lrb=tid>>6;
    float mu=p.cs2[f]*(1.f/NN);
    float var=p.cs2[FH2+f]*(1.f/NN)-mu*mu;
    float rinv=rsqrtf(var+BNEPS);
    float sc=p.g2[f]*rinv, sh=p.be2[f]-mu*sc;
    int rb=blockIdx.x*48;
    for (int pass=0;pass<12;pass++){
      int lr=pass*4+lrb, row=rb+lr;
      float d=p.dis[row];
      float acc=d*fmaxf(p.P2[row*FH2+f]*sc+sh,0.f);
      int beg=p.rowptr[row], n=p.cnt[row];
      for(int j=0;j<n;j++){
        int c=p.csr_col[beg+j];
        acc+=p.csr_w[beg+j]*fmaxf(p.P2[c*FH2+f]*sc+sh,0.f);
      }
      At[lr][f]=d*acc;
    }
    __syncthreads();
    int fo=tid&63;
    float sa=0.f, qa=0.f;
    for(int o=tid;o<48*FH2;o+=NT){
      int lr=o>>6;
      float s=p.b3[fo];
      #pragma unroll
      for(int fi=0;fi<FH2;fi++) s+=At[lr][fi]*p.w3[fi*FH2+fo];
      p.P3[(rb+lr)*FH2+fo]=s;
      sa+=s; qa+=s*s;
    }
    __shared__ float lcs[FH2],lcq[FH2];
    if(tid<FH2){lcs[tid]=0.f;lcq[tid]=0.f;}
    __syncthreads();
    atomicAdd(&lcs[fo],sa); atomicAdd(&lcq[fo],qa);
    __syncthreads();
    if(tid<FH2){atomicAdd(&p.cs3[tid],lcs[tid]); atomicAdd(&p.cs3[FH2+tid],lcq[tid]);}
  }
  grid.sync();

  // ---- P7: pool — BN3 on the fly, per-graph max via int atomicMax (vals >= 0) ----
  {
    int b = blockIdx.x & 15, chunk = blockIdx.x >> 4;
    int lo=0,hi=NN;
    while(lo<hi){int m=(lo+hi)>>1; if(getIdx(p.batch,m,isb64)<b) lo=m+1; else hi=m;}
    int start=lo; lo=start; hi=NN;
    while(lo<hi){int m=(lo+hi)>>1; if(getIdx(p.batch,m,isb64)<b+1) lo=m+1; else hi=m;}
    int end=lo;
    int f=tid&63, grp=tid>>6;
    float mu=p.cs3[f]*(1.f/NN);
    float var=p.cs3[FH2+f]*(1.f/NN)-mu*mu;
    float rinv=rsqrtf(var+BNEPS);
    float sc=p.g3[f]*rinv, sh=p.be3[f]-mu*sc;
    float m=0.f;
    for (int i=start+chunk*4+grp; i<end; i+=64)
      m = fmaxf(m, p.P3[(long)i*FH2+f]*sc+sh);
    __shared__ float shm[4][64];
    shm[grp][f]=m;
    __syncthreads();
    if (grp==0){
      float v=fmaxf(fmaxf(shm[0][f],shm[1][f]),fmaxf(shm[2][f],shm[3][f]));
      atomicMax((int*)&p.embf[b*64+f], __float_as_int(v));
    }
  }
  grid.sync();

  // ---- P8: fc1 z (row x col parallel) + emb copy to out ----
  if (gtid < BG*512){
    int r=gtid>>9, c=gtid&511;
    float s=p.bf1[c];
    #pragma unroll 8
    for(int k=0;k<64;k++) s+=p.embf[r*64+k]*p.wf1[k*512+c];
    p.z1[gtid]=s;
  }
  if (gtid < BG*64) p.out[BG*NCL+gtid]=p.embf[gtid];
  grid.sync();

  // ---- P9: fc1 BN+relu (col-local over 16 rows) ----
  if (gtid < 512){
    int c=gtid;
    float zv[BG]; float s=0.f,q=0.f;
    #pragma unroll
    for(int r=0;r<BG;r++){ float z=p.z1[r*512+c]; zv[r]=z; s+=z; q+=z*z; }
    float mean=s*(1.f/BG), var=q*(1.f/BG)-mean*mean;
    float inv=rsqrtf(var+BNEPS);
    float gg=p.gf1[c], bb=p.bef1[c];
    #pragma unroll
    for(int r=0;r<BG;r++) p.s1g[r*512+c]=fmaxf(gg*(zv[r]-mean)*inv+bb,0.f);
  }
  grid.sync();

  // ---- P10: fc2 z ----
  if (gtid < BG*256){
    int r=gtid>>8, c=gtid&255;
    float s=p.bf2[c];
    #pragma unroll 8
    for(int k=0;k<512;k++) s+=p.s1g[r*512+k]*p.wf2[k*256+c];
    p.z2[gtid]=s;
  }
  grid.sync();

  // ---- P11: fc2 BN+relu ----
  if (gtid < 256){
    int c=gtid;
    float zv[BG]; float s=0.f,q=0.f;
    #pragma unroll
    for(int r=0;r<BG;r++){ float z=p.z2[r*256+c]; zv[r]=z; s+=z; q+=z*z; }
    float mean=s*(1.f/BG), var=q*(1.f/BG)-mean*mean;
    float inv=rsqrtf(var+BNEPS);
    float gg=p.gf2[c], bb=p.bef2[c];
    #pragma unroll
    for(int r=0;r<BG;r++) p.s2g[r*256+c]=fmaxf(gg*(zv[r]-mean)*inv+bb,0.f);
  }
  grid.sync();

  // ---- P12: fc3 + log_softmax (block 0) ----
  if (blockIdx.x==0){
    __shared__ float s2[BG*256];
    __shared__ float sl[BG*NCL];
    for (int i=tid;i<BG*256;i+=NT) s2[i]=p.s2g[i];
    __syncthreads();
    if (tid<BG*NCL){
      int r=tid/NCL, c=tid-r*NCL;
      float s=p.bf3[c];
      for(int k=0;k<256;k++) s+=s2[r*256+k]*p.wf3[k*NCL+c];
      sl[tid]=s;
    }
    __syncthreads();
    if (tid<BG){
      float m=-1e30f;
      for(int c=0;c<NCL;c++) m=fmaxf(m,sl[tid*NCL+c]);
      float s=0.f;
      for(int c=0;c<NCL;c++) s+=expf(sl[tid*NCL+c]-m);
      float lg=logf(s)+m;
      for(int c=0;c<NCL;c++) p.out[tid*NCL+c]=sl[tid*NCL+c]-lg;
    }
  }
}

extern "C" void kernel_launch(void* const* d_in, const int* in_sizes, int n_in,
                              void* d_out, int out_size, void* d_ws, size_t ws_size,
                              hipStream_t stream){
  Params p;
  p.x    = (const float*)d_in[0];
  p.ea   = (const float*)d_in[1];
  p.we   = (const float*)d_in[2];
  p.bedg = (const float*)d_in[3];
  p.w1 = (const float*)d_in[4];  p.b1 = (const float*)d_in[5];
  p.g1 = (const float*)d_in[6];  p.be1= (const float*)d_in[7];
  p.w2 = (const float*)d_in[8];  p.b2 = (const float*)d_in[9];
  p.g2 = (const float*)d_in[10]; p.be2= (const float*)d_in[11];
  p.w3 = (const float*)d_in[12]; p.b3 = (const float*)d_in[13];
  p.g3 = (const float*)d_in[14]; p.be3= (const float*)d_in[15];
  p.wf1= (const float*)d_in[16]; p.bf1= (const float*)d_in[17];
  p.gf1= (const float*)d_in[18]; p.bef1=(const float*)d_in[19];
  p.wf2= (const float*)d_in[20]; p.bf2= (const float*)d_in[21];
  p.gf2= (const float*)d_in[22]; p.bef2=(const float*)d_in[23];
  p.wf3= (const float*)d_in[24]; p.bf3= (const float*)d_in[25];
  p.ei = d_in[26];
  p.batch = d_in[27];
  p.out = (float*)d_out;

  float* ws = (float*)d_ws;
  p.deg  = ws; ws += NN;
  p.dis  = ws; ws += NN;
  p.csr_w= ws; ws += EE;
  p.P1   = ws; ws += NN*FH1;
  p.P2   = ws; ws += NN*FH2;
  p.P3   = ws; ws += NN*FH2;
  p.cs1  = ws; ws += 128;
  p.cs2  = ws; ws += 128;
  p.cs3  = ws; ws += 128;
  p.embf = ws; ws += BG*64;
  p.z1   = ws; ws += BG*512;
  p.s1g  = ws; ws += BG*512;
  p.z2   = ws; ws += BG*256;
  p.s2g  = ws; ws += BG*256;
  int* wi = (int*)ws;
  p.cnt    = wi; wi += NN;
  p.rowptr = wi; wi += NN;
  p.fillp  = wi; wi += NN;
  p.csr_col= wi; wi += EE;
  p.bsum   = wi; wi += 64;
  p.flags  = wi; wi += 2;

  void* args[] = { &p };
  hipLaunchCooperativeKernel((const void*)mega, dim3(NB), dim3(NT), args, 0, stream);
}

// Round 8
// 457.613 us; speedup vs baseline: 1.9750x; 1.9750x over previous
//
#include <hip/hip_runtime.h>
#include <hip/hip_bf16.h>

#define NN   12288
#define EE   393216
#define BG   16
#define FIN  15
#define FH1  32
#define FH2  64
#define NCL  11
#define BNEPS 1e-5f

typedef unsigned short u16;
static inline int cdiv(long a, long b){ return (int)((a + b - 1) / b); }

__device__ __forceinline__ int getIdx(const void* p, long i, int is64){
  return is64 ? (int)((const long long*)p)[i] : ((const int*)p)[i];
}

// ---- pre: init deg/cnt, zero colstats, detect int width (block 0) ----
__global__ void k_pre(float* deg, int* cnt, float* cs1, float* cs2, float* cs3,
                      const void* ei, const void* batch, int* flags){
  int g = blockIdx.x*256 + threadIdx.x;
  if (g < NN){ deg[g] = 1.0f; cnt[g] = 0; }
  if (g < 128) cs1[g] = 0.f;
  else if (g < 256) cs2[g-128] = 0.f;
  else if (g < 384) cs3[g-256] = 0.f;
  if (blockIdx.x == 0 && threadIdx.x < 64){
    const int* a = (const int*)ei;
    unsigned long long m0 = __ballot(a[2*threadIdx.x + 1] == 0);
    const int* b = (const int*)batch;
    int j = 96*threadIdx.x;
    unsigned long long m1 = __ballot(b[2*j + 1] == 0);
    if (threadIdx.x == 0){
      flags[0] = (m0 == ~0ull) ? 1 : 0;
      flags[1] = (m1 == ~0ull) ? 1 : 0;
    }
  }
}

// ---- edge pass 1: weighted degree + row counts ----
__global__ void k_edge(const float* ea, const float* we, const float* bedg,
                       const void* ei, const int* flags, float* deg, int* cnt){
  int e = blockIdx.x*256 + threadIdx.x;
  if (e >= EE) return;
  int is64 = flags[0];
  float z = ea[2*e]*we[0] + ea[2*e+1]*we[1] + bedg[0];
  float w = 1.0f/(1.0f + expf(-z));
  int r = getIdx(ei, e, is64);
  atomicAdd(&deg[r], w);
  atomicAdd(&cnt[r], 1);
}

// ---- scan A: per-block inclusive scan of cnt -> rowptr (exclusive), bsum ----
__global__ void k_scanA(const int* cnt, int* rowptr, int* bsum){
  __shared__ int sbuf[256];
  int i = blockIdx.x*256 + threadIdx.x;
  int v = cnt[i];
  sbuf[threadIdx.x] = v;
  __syncthreads();
  for (int off = 1; off < 256; off <<= 1){
    int add = (threadIdx.x >= off) ? sbuf[threadIdx.x - off] : 0;
    __syncthreads();
    sbuf[threadIdx.x] += add;
    __syncthreads();
  }
  rowptr[i] = sbuf[threadIdx.x] - v;
  if (threadIdx.x == 255) bsum[blockIdx.x] = sbuf[255];
}

// ---- scan B: every block re-scans the 48 partials, applies offset; dis ----
__global__ void k_scanB(const int* bsum, const float* deg,
                        int* rowptr, int* fillp, float* dis){
  __shared__ int sb[64], sbx[64];
  if (threadIdx.x < 64){
    int v = (threadIdx.x < 48) ? bsum[threadIdx.x] : 0;
    sb[threadIdx.x] = v;
  }
  __syncthreads();
  for (int off = 1; off < 64; off <<= 1){
    int add = (threadIdx.x < 64 && threadIdx.x >= off) ? sb[threadIdx.x - off] : 0;
    __syncthreads();
    if (threadIdx.x < 64) sb[threadIdx.x] += add;
    __syncthreads();
  }
  if (threadIdx.x < 64){
    int incl = sb[threadIdx.x];
    int v = (threadIdx.x < 48) ? bsum[threadIdx.x] : 0;
    sbx[threadIdx.x] = incl - v;
  }
  __syncthreads();
  int off = sbx[blockIdx.x];
  int i = blockIdx.x*256 + threadIdx.x;
  int rp = rowptr[i] + off;
  rowptr[i] = rp;
  fillp[i]  = rp;
  dis[i]    = rsqrtf(deg[i]);
}

// ---- edge pass 2: fill CSR (u16 col + premultiplied w*dis[col]) ----
__global__ void k_fill(const float* ea, const float* we, const float* bedg,
                       const void* ei, const int* flags, const float* dis,
                       int* fillp, u16* csr_col, float* csr_w){
  int e = blockIdx.x*256 + threadIdx.x;
  if (e >= EE) return;
  int is64 = flags[0];
  int r = getIdx(ei, e, is64);
  int c = getIdx(ei, (long)EE + e, is64);
  float z = ea[2*e]*we[0] + ea[2*e+1]*we[1] + bedg[0];
  float w = 1.0f/(1.0f + expf(-z));
  int slot = atomicAdd(&fillp[r], 1);
  csr_col[slot] = (u16)c;
  csr_w[slot] = w * dis[c];
}

// ---- fused GCN layer: gather (+BN/relu on load) -> LDS tile -> GEMM -> P, colstats
// FP threads per row (FP>=F), R=256/FP rows per tile; grid-stride over tiles.
template<int F, int FP, int FO, int APPLY_BN>
__global__ void __launch_bounds__(256) k_layer(
    const float* Hin, const float* csin, const float* g, const float* be,
    const float* W, const float* bias, const int* rowptr, const int* cnt,
    const u16* csr_col, const float* csr_w, const float* dis,
    float* Pout, float* csout, int ntiles){
  const int R = 256/FP;
  __shared__ float At[R][FP];
  __shared__ float lcs[FO], lcq[FO];
  if (threadIdx.x < FO){ lcs[threadIdx.x] = 0.f; lcq[threadIdx.x] = 0.f; }
  int f = threadIdx.x % FP, lr = threadIdx.x / FP;
  float sc = 1.f, sh = 0.f;
  if (APPLY_BN && f < F){
    float mu  = csin[f]*(1.0f/NN);
    float var = csin[F+f]*(1.0f/NN) - mu*mu;
    float rinv = rsqrtf(var + BNEPS);
    sc = g[f]*rinv; sh = be[f] - mu*sc;
  }
  const int fo = threadIdx.x % FO;     // 256 % FO == 0
  __syncthreads();
  for (int tile = blockIdx.x; tile < ntiles; tile += gridDim.x){
    int row = tile*R + lr;
    if (f < F){
      float d = dis[row];
      float v0 = Hin[row*F + f];
      if (APPLY_BN) v0 = fmaxf(v0*sc + sh, 0.f);
      float acc = d * v0;                       // self loop
      int beg = rowptr[row], n = cnt[row];
      for (int j = 0; j < n; j++){
        int c = csr_col[beg + j];
        float hv = Hin[c*F + f];
        if (APPLY_BN) hv = fmaxf(hv*sc + sh, 0.f);
        acc += csr_w[beg + j] * hv;
      }
      At[lr][f] = d * acc;
    }
    __syncthreads();
    for (int o = threadIdx.x; o < R*FO; o += 256){
      int l = o / FO;
      float s = bias[fo];
      #pragma unroll
      for (int fi = 0; fi < F; fi++) s += At[l][fi] * W[fi*FO + fo];
      Pout[(tile*R + l)*FO + fo] = s;
      atomicAdd(&lcs[fo], s);
      atomicAdd(&lcq[fo], s*s);
    }
    __syncthreads();
  }
  if (threadIdx.x < FO){
    atomicAdd(&csout[threadIdx.x],      lcs[threadIdx.x]);
    atomicAdd(&csout[FO + threadIdx.x], lcq[threadIdx.x]);
  }
}

// ---- pool: BN3 on load, per-graph max, write embf + emb part of out ----
__global__ void k_pool(const float* P3, const float* cs3, const float* g3,
                       const float* be3, const void* batch, const int* flags,
                       float* embf, float* out){
  int is64 = flags[1];
  int b = blockIdx.x;
  int lo = 0, hi = NN;
  while (lo < hi){ int m = (lo+hi)>>1; if (getIdx(batch, m, is64) < b) lo = m+1; else hi = m; }
  int start = lo;
  lo = start; hi = NN;
  while (lo < hi){ int m = (lo+hi)>>1; if (getIdx(batch, m, is64) < b+1) lo = m+1; else hi = m; }
  int end = lo;
  int f = threadIdx.x & 63, grp = threadIdx.x >> 6;
  float mu  = cs3[f]*(1.0f/NN);
  float var = cs3[FH2+f]*(1.0f/NN) - mu*mu;
  float rinv = rsqrtf(var + BNEPS);
  float sc = g3[f]*rinv, sh = be3[f] - mu*sc;
  float m = 0.0f;
  for (int i = start + grp; i < end; i += 4)
    m = fmaxf(m, P3[(long)i*FH2 + f]*sc + sh);
  __shared__ float shm[4][64];
  shm[grp][f] = m;
  __syncthreads();
  if (grp == 0){
    float v = fmaxf(fmaxf(shm[0][f], shm[1][f]), fmaxf(shm[2][f], shm[3][f]));
    embf[b*64 + f] = v;
    out[BG*NCL + b*64 + f] = v;
  }
}

// ---- head fc1 z: thread per (r,c), 16x512 ----
__global__ void k_fc1z(const float* embf, const float* wf1, const float* bf1, float* z1){
  int t = blockIdx.x*256 + threadIdx.x;
  if (t >= BG*512) return;
  int r = t >> 9, c = t & 511;
  float s = bf1[c];
  #pragma unroll 8
  for (int k = 0; k < 64; k++) s += embf[r*64 + k]*wf1[k*512 + c];
  z1[t] = s;
}

// ---- head fc1 BN+relu: thread per column ----
__global__ void k_fc1bn(const float* z1, const float* gf1, const float* bef1, float* s1g){
  int c = blockIdx.x*256 + threadIdx.x;
  if (c >= 512) return;
  float zv[BG]; float s = 0.f, q = 0.f;
  #pragma unroll
  for (int r = 0; r < BG; r++){ float z = z1[r*512 + c]; zv[r] = z; s += z; q += z*z; }
  float mean = s*(1.f/BG), var = q*(1.f/BG) - mean*mean;
  float inv = rsqrtf(var + BNEPS);
  float gg = gf1[c], bb = bef1[c];
  #pragma unroll
  for (int r = 0; r < BG; r++) s1g[r*512 + c] = fmaxf(gg*(zv[r]-mean)*inv + bb, 0.f);
}

// ---- head fc2 z: thread per (r,c), 16x256 ----
__global__ void k_fc2z(const float* s1g, const float* wf2, const float* bf2, float* z2){
  int t = blockIdx.x*256 + threadIdx.x;
  if (t >= BG*256) return;
  int r = t >> 8, c = t & 255;
  float s = bf2[c];
  #pragma unroll 8
  for (int k = 0; k < 512; k++) s += s1g[r*512 + k]*wf2[k*256 + c];
  z2[t] = s;
}

// ---- head fc2 BN+relu ----
__global__ void k_fc2bn(const float* z2, const float* gf2, const float* bef2, float* s2g){
  int c = threadIdx.x;
  float zv[BG]; float s = 0.f, q = 0.f;
  #pragma unroll
  for (int r = 0; r < BG; r++){ float z = z2[r*256 + c]; zv[r] = z; s += z; q += z*z; }
  float mean = s*(1.f/BG), var = q*(1.f/BG) - mean*mean;
  float inv = rsqrtf(var + BNEPS);
  float gg = gf2[c], bb = bef2[c];
  #pragma unroll
  for (int r = 0; r < BG; r++) s2g[r*256 + c] = fmaxf(gg*(zv[r]-mean)*inv + bb, 0.f);
}

// ---- head fc3 + log_softmax ----
__global__ void k_fc3(const float* s2g, const float* wf3, const float* bf3, float* out){
  __shared__ float s2[BG*256];
  __shared__ float sl[BG*NCL];
  int t = threadIdx.x;
  for (int i = t; i < BG*256; i += 256) s2[i] = s2g[i];
  __syncthreads();
  if (t < BG*NCL){
    int r = t / NCL, c = t - r*NCL;
    float s = bf3[c];
    for (int k = 0; k < 256; k++) s += s2[r*256 + k]*wf3[k*NCL + c];
    sl[t] = s;
  }
  __syncthreads();
  if (t < BG){
    float m = -1e30f;
    for (int c = 0; c < NCL; c++) m = fmaxf(m, sl[t*NCL + c]);
    float s = 0.f;
    for (int c = 0; c < NCL; c++) s += expf(sl[t*NCL + c] - m);
    float lg = logf(s) + m;
    for (int c = 0; c < NCL; c++) out[t*NCL + c] = sl[t*NCL + c] - lg;
  }
}

extern "C" void kernel_launch(void* const* d_in, const int* in_sizes, int n_in,
                              void* d_out, int out_size, void* d_ws, size_t ws_size,
                              hipStream_t stream){
  const float* x    = (const float*)d_in[0];
  const float* ea   = (const float*)d_in[1];
  const float* we   = (const float*)d_in[2];
  const float* bedg = (const float*)d_in[3];
  const float* w1   = (const float*)d_in[4];  const float* b1  = (const float*)d_in[5];
  const float* g1   = (const float*)d_in[6];  const float* be1 = (const float*)d_in[7];
  const float* w2   = (const float*)d_in[8];  const float* b2  = (const float*)d_in[9];
  const float* g2   = (const float*)d_in[10]; const float* be2 = (const float*)d_in[11];
  const float* w3   = (const float*)d_in[12]; const float* b3  = (const float*)d_in[13];
  const float* g3   = (const float*)d_in[14]; const float* be3 = (const float*)d_in[15];
  const float* wf1  = (const float*)d_in[16]; const float* bf1 = (const float*)d_in[17];
  const float* gf1  = (const float*)d_in[18]; const float* bef1= (const float*)d_in[19];
  const float* wf2  = (const float*)d_in[20]; const float* bf2 = (const float*)d_in[21];
  const float* gf2  = (const float*)d_in[22]; const float* bef2= (const float*)d_in[23];
  const float* wf3  = (const float*)d_in[24]; const float* bf3 = (const float*)d_in[25];
  const void* ei    = d_in[26];
  const void* batch = d_in[27];
  float* out = (float*)d_out;

  float* ws = (float*)d_ws;
  float* deg   = ws; ws += NN;
  float* dis   = ws; ws += NN;
  float* csr_w = ws; ws += EE;
  float* P1    = ws; ws += NN*FH1;
  float* P2    = ws; ws += NN*FH2;
  float* P3    = ws; ws += NN*FH2;
  float* cs1   = ws; ws += 128;
  float* cs2   = ws; ws += 128;
  float* cs3   = ws; ws += 128;
  float* embf  = ws; ws += BG*64;
  float* z1    = ws; ws += BG*512;
  float* s1g   = ws; ws += BG*512;
  float* z2    = ws; ws += BG*256;
  float* s2g   = ws; ws += BG*256;
  int* wi = (int*)ws;
  int* cnt    = wi; wi += NN;
  int* rowptr = wi; wi += NN;
  int* fillp  = wi; wi += NN;
  int* bsum   = wi; wi += 64;
  int* flags  = wi; wi += 2;
  u16* csr_col = (u16*)wi;

  k_pre<<<48, 256, 0, stream>>>(deg, cnt, cs1, cs2, cs3, ei, batch, flags);
  k_edge<<<cdiv(EE,256), 256, 0, stream>>>(ea, we, bedg, ei, flags, deg, cnt);
  k_scanA<<<48, 256, 0, stream>>>(cnt, rowptr, bsum);
  k_scanB<<<48, 256, 0, stream>>>(bsum, deg, rowptr, fillp, dis);
  k_fill<<<cdiv(EE,256), 256, 0, stream>>>(ea, we, bedg, ei, flags, dis, fillp, csr_col, csr_w);

  // layer 1: x(15) -> P1(32), no BN on load
  k_layer<FIN,16,FH1,0><<<768, 256, 0, stream>>>(x, nullptr, nullptr, nullptr,
      w1, b1, rowptr, cnt, csr_col, csr_w, dis, P1, cs1, NN/16);
  // layer 2: BN1(P1)(32) -> P2(64)
  k_layer<FH1,32,FH2,1><<<768, 256, 0, stream>>>(P1, cs1, g1, be1,
      w2, b2, rowptr, cnt, csr_col, csr_w, dis, P2, cs2, NN/8);
  // layer 3: BN2(P2)(64) -> P3(64)
  k_layer<FH2,64,FH2,1><<<768, 256, 0, stream>>>(P2, cs2, g2, be2,
      w3, b3, rowptr, cnt, csr_col, csr_w, dis, P3, cs3, NN/4);

  k_pool<<<BG, 256, 0, stream>>>(P3, cs3, g3, be3, batch, flags, embf, out);
  k_fc1z<<<32, 256, 0, stream>>>(embf, wf1, bf1, z1);
  k_fc1bn<<<2, 256, 0, stream>>>(z1, gf1, bef1, s1g);
  k_fc2z<<<16, 256, 0, stream>>>(s1g, wf2, bf2, z2);
  k_fc2bn<<<1, 256, 0, stream>>>(z2, gf2, bef2, s2g);
  k_fc3<<<1, 256, 0, stream>>>(s2g, wf3, bf3, out);
}

// Round 9
// 308.907 us; speedup vs baseline: 2.9258x; 1.4814x over previous
//
#include <hip/hip_runtime.h>
#include <hip/hip_bf16.h>

#define NN   12288
#define EE   393216
#define EEPAD (EE + 8*NN)
#define BG   16
#define FIN  15
#define FH1  32
#define FH2  64
#define NCL  11
#define BNEPS 1e-5f
#define NBANK 32

typedef unsigned short u16;
static inline int cdiv(long a, long b){ return (int)((a + b - 1) / b); }

__device__ __forceinline__ int getIdx(const void* p, long i, int is64){
  return is64 ? (int)((const long long*)p)[i] : ((const int*)p)[i];
}

// ---- pre: init deg/cnt, zero colstat banks, detect int width ----
__global__ void k_pre(float* deg, int* cnt, float* csp1, float* csp2, float* csp3,
                      const void* ei, const void* batch, int* flags){
  int g = blockIdx.x*256 + threadIdx.x;
  if (g < NN){ deg[g] = 1.0f; cnt[g] = 0; }
  if (g < NBANK*128){ csp1[g] = 0.f; csp2[g] = 0.f; csp3[g] = 0.f; }
  if (blockIdx.x == 0 && threadIdx.x < 64){
    const int* a = (const int*)ei;
    unsigned long long m0 = __ballot(a[2*threadIdx.x + 1] == 0);
    const int* b = (const int*)batch;
    int j = 96*threadIdx.x;
    unsigned long long m1 = __ballot(b[2*j + 1] == 0);
    if (threadIdx.x == 0){
      flags[0] = (m0 == ~0ull) ? 1 : 0;
      flags[1] = (m1 == ~0ull) ? 1 : 0;
    }
  }
}

// ---- edge pass 1: weighted degree + row counts ----
__global__ void k_edge(const float* ea, const float* we, const float* bedg,
                       const void* ei, const int* flags, float* deg, int* cnt){
  int e = blockIdx.x*256 + threadIdx.x;
  if (e >= EE) return;
  int is64 = flags[0];
  float z = ea[2*e]*we[0] + ea[2*e+1]*we[1] + bedg[0];
  float w = 1.0f/(1.0f + expf(-z));
  int r = getIdx(ei, e, is64);
  atomicAdd(&deg[r], w);
  atomicAdd(&cnt[r], 1);
}

// ---- scan A: per-block scan of PADDED counts -> rowptr (exclusive), bsum ----
__global__ void k_scanA(const int* cnt, int* rowptr, int* bsum){
  __shared__ int sbuf[256];
  int i = blockIdx.x*256 + threadIdx.x;
  int v = (cnt[i] + 7) & ~7;            // pad row to multiple of 8 slots
  sbuf[threadIdx.x] = v;
  __syncthreads();
  for (int off = 1; off < 256; off <<= 1){
    int add = (threadIdx.x >= off) ? sbuf[threadIdx.x - off] : 0;
    __syncthreads();
    sbuf[threadIdx.x] += add;
    __syncthreads();
  }
  rowptr[i] = sbuf[threadIdx.x] - v;
  if (threadIdx.x == 255) bsum[blockIdx.x] = sbuf[255];
}

// ---- scan B: apply block offsets; init fillp, dis; zero the pad slots ----
__global__ void k_scanB(const int* bsum, const float* deg, const int* cnt,
                        int* rowptr, int* fillp, float* dis,
                        u16* csr_col, float* csr_w){
  __shared__ int sbx[64];
  if (threadIdx.x < 64){
    int v = (threadIdx.x < 48) ? bsum[threadIdx.x] : 0;
    sbx[threadIdx.x] = v;
  }
  __syncthreads();
  for (int off = 1; off < 64; off <<= 1){
    int add = (threadIdx.x < 64 && threadIdx.x >= off) ? sbx[threadIdx.x - off] : 0;
    __syncthreads();
    if (threadIdx.x < 64) sbx[threadIdx.x] += add;
    __syncthreads();
  }
  __syncthreads();
  int off = (blockIdx.x == 0) ? 0 : sbx[blockIdx.x - 1];
  int i = blockIdx.x*256 + threadIdx.x;
  int rp = rowptr[i] + off;
  rowptr[i] = rp;
  fillp[i]  = rp;
  dis[i]    = rsqrtf(deg[i]);
  int n = cnt[i], np = (n + 7) & ~7;
  for (int s = rp + n; s < rp + np; s++){ csr_w[s] = 0.f; csr_col[s] = 0; }
}

// ---- edge pass 2: fill CSR (u16 col + premultiplied w*dis[col]) ----
__global__ void k_fill(const float* ea, const float* we, const float* bedg,
                       const void* ei, const int* flags, const float* dis,
                       int* fillp, u16* csr_col, float* csr_w){
  int e = blockIdx.x*256 + threadIdx.x;
  if (e >= EE) return;
  int is64 = flags[0];
  int r = getIdx(ei, e, is64);
  int c = getIdx(ei, (long)EE + e, is64);
  float z = ea[2*e]*we[0] + ea[2*e+1]*we[1] + bedg[0];
  float w = 1.0f/(1.0f + expf(-z));
  int slot = atomicAdd(&fillp[r], 1);
  csr_col[slot] = (u16)c;
  csr_w[slot] = w * dis[c];
}

// ---- fused GCN layer, one tile per block ----
// gather (+BN/relu on load) with 8-wide chunked neighbor loads -> LDS -> GEMM
template<int F, int FP, int FO, int APPLY_BN>
__global__ void __launch_bounds__(256) k_layer(
    const float* __restrict__ Hin, const float* __restrict__ csin,
    const float* __restrict__ g, const float* __restrict__ be,
    const float* __restrict__ W, const float* __restrict__ bias,
    const int* __restrict__ rowptr, const int* __restrict__ cnt,
    const u16* __restrict__ csr_col, const float* __restrict__ csr_w,
    const float* __restrict__ dis, float* __restrict__ Pout,
    float* __restrict__ csout){
  const int R = 256/FP;
  __shared__ float At[R][FP];
  __shared__ float lcs[FO], lcq[FO];
  if (threadIdx.x < FO){ lcs[threadIdx.x] = 0.f; lcq[threadIdx.x] = 0.f; }
  int f = threadIdx.x % FP, lr = threadIdx.x / FP;
  float sc = 1.f, sh = 0.f;
  if (APPLY_BN && f < F){
    float s = 0.f, q = 0.f;
    #pragma unroll
    for (int b = 0; b < NBANK; b++){ s += csin[b*128 + f]; q += csin[b*128 + 64 + f]; }
    float mu  = s*(1.0f/NN);
    float var = q*(1.0f/NN) - mu*mu;
    float rinv = rsqrtf(var + BNEPS);
    sc = g[f]*rinv; sh = be[f] - mu*sc;
  }
  int row = blockIdx.x*R + lr;
  if (f < F){
    float d = dis[row];
    float v0 = Hin[row*F + f];
    if (APPLY_BN) v0 = fmaxf(v0*sc + sh, 0.f);
    float acc = d * v0;                       // self loop
    int beg = rowptr[row];
    int nch = (cnt[row] + 7) >> 3;
    const uint4*  cb = (const uint4*)(csr_col + beg);
    const float4* wb = (const float4*)(csr_w + beg);
    for (int ch = 0; ch < nch; ch++){
      uint4 cw = cb[ch];
      const u16* cc = (const u16*)&cw;
      float4 wA = wb[2*ch], wB = wb[2*ch+1];
      float h0 = Hin[(int)cc[0]*F + f];
      float h1 = Hin[(int)cc[1]*F + f];
      float h2 = Hin[(int)cc[2]*F + f];
      float h3 = Hin[(int)cc[3]*F + f];
      float h4 = Hin[(int)cc[4]*F + f];
      float h5 = Hin[(int)cc[5]*F + f];
      float h6 = Hin[(int)cc[6]*F + f];
      float h7 = Hin[(int)cc[7]*F + f];
      if (APPLY_BN){
        h0 = fmaxf(h0*sc + sh, 0.f); h1 = fmaxf(h1*sc + sh, 0.f);
        h2 = fmaxf(h2*sc + sh, 0.f); h3 = fmaxf(h3*sc + sh, 0.f);
        h4 = fmaxf(h4*sc + sh, 0.f); h5 = fmaxf(h5*sc + sh, 0.f);
        h6 = fmaxf(h6*sc + sh, 0.f); h7 = fmaxf(h7*sc + sh, 0.f);
      }
      acc += wA.x*h0 + wA.y*h1 + wA.z*h2 + wA.w*h3
           + wB.x*h4 + wB.y*h5 + wB.z*h6 + wB.w*h7;
    }
    At[lr][f] = d * acc;
  }
  __syncthreads();
  const int fo = threadIdx.x % FO;     // 256 % FO == 0
  float bb = bias[fo];
  for (int o = threadIdx.x; o < R*FO; o += 256){
    int l = o / FO;
    float s = bb;
    #pragma unroll
    for (int fi = 0; fi < F; fi++) s += At[l][fi] * W[fi*FO + fo];
    Pout[(blockIdx.x*R + l)*FO + fo] = s;
    atomicAdd(&lcs[fo], s);
    atomicAdd(&lcq[fo], s*s);
  }
  __syncthreads();
  if (threadIdx.x < FO){
    int bank = blockIdx.x & (NBANK-1);
    atomicAdd(&csout[bank*128 + threadIdx.x],      lcs[threadIdx.x]);
    atomicAdd(&csout[bank*128 + 64 + threadIdx.x], lcq[threadIdx.x]);
  }
}

// ---- pool: BN3 on load, per-graph max, write embf + emb part of out ----
__global__ void k_pool(const float* P3, const float* cs3, const float* g3,
                       const float* be3, const void* batch, const int* flags,
                       float* embf, float* out){
  int is64 = flags[1];
  int b = blockIdx.x;
  int lo = 0, hi = NN;
  while (lo < hi){ int m = (lo+hi)>>1; if (getIdx(batch, m, is64) < b) lo = m+1; else hi = m; }
  int start = lo;
  lo = start; hi = NN;
  while (lo < hi){ int m = (lo+hi)>>1; if (getIdx(batch, m, is64) < b+1) lo = m+1; else hi = m; }
  int end = lo;
  int f = threadIdx.x & 63, grp = threadIdx.x >> 6;
  float s = 0.f, q = 0.f;
  #pragma unroll
  for (int bk = 0; bk < NBANK; bk++){ s += cs3[bk*128 + f]; q += cs3[bk*128 + 64 + f]; }
  float mu  = s*(1.0f/NN);
  float var = q*(1.0f/NN) - mu*mu;
  float rinv = rsqrtf(var + BNEPS);
  float sc = g3[f]*rinv, sh = be3[f] - mu*sc;
  float m = 0.0f;
  for (int i = start + grp; i < end; i += 4)
    m = fmaxf(m, P3[(long)i*FH2 + f]*sc + sh);
  __shared__ float shm[4][64];
  shm[grp][f] = m;
  __syncthreads();
  if (grp == 0){
    float v = fmaxf(fmaxf(shm[0][f], shm[1][f]), fmaxf(shm[2][f], shm[3][f]));
    embf[b*64 + f] = v;
    out[BG*NCL + b*64 + f] = v;
  }
}

// ---- head fc1 + BN + relu: wave per column (512 cols, 128 blocks x 4 waves) ----
__global__ void __launch_bounds__(256) k_fcA(const float* embf, const float* wf1,
    const float* bf1, const float* gf1, const float* bef1, float* s1g){
  int c = blockIdx.x*4 + (threadIdx.x >> 6);
  int l = threadIdx.x & 63;
  float wcol = wf1[l*512 + c];
  float z[BG];
  #pragma unroll
  for (int r = 0; r < BG; r++){
    float v = embf[r*64 + l] * wcol;
    #pragma unroll
    for (int off = 32; off > 0; off >>= 1) v += __shfl_down(v, off);
    z[r] = v;                 // valid on lane 0
  }
  if (l == 0){
    float bb = bf1[c];
    float s = 0.f, q = 0.f;
    #pragma unroll
    for (int r = 0; r < BG; r++){ float zr = z[r] + bb; s += zr; q += zr*zr; }
    float mean = s*(1.f/BG), var = q*(1.f/BG) - mean*mean;
    float inv = rsqrtf(var + BNEPS);
    float gg = gf1[c], b2 = bef1[c];
    #pragma unroll
    for (int r = 0; r < BG; r++)
      s1g[r*512 + c] = fmaxf(gg*(z[r] + bb - mean)*inv + b2, 0.f);
  }
}

// ---- head fc2 + BN + relu: wave per column (256 cols, 64 blocks x 4 waves) ----
__global__ void __launch_bounds__(256) k_fcB(const float* s1g, const float* wf2,
    const float* bf2, const float* gf2, const float* bef2, float* s2g){
  int c = blockIdx.x*4 + (threadIdx.x >> 6);
  int l = threadIdx.x & 63;
  float wreg[8];
  #pragma unroll
  for (int j = 0; j < 8; j++) wreg[j] = wf2[(l + 64*j)*256 + c];
  float z[BG];
  #pragma unroll
  for (int r = 0; r < BG; r++){
    float v = 0.f;
    #pragma unroll
    for (int j = 0; j < 8; j++) v += s1g[r*512 + l + 64*j] * wreg[j];
    #pragma unroll
    for (int off = 32; off > 0; off >>= 1) v += __shfl_down(v, off);
    z[r] = v;
  }
  if (l == 0){
    float bb = bf2[c];
    float s = 0.f, q = 0.f;
    #pragma unroll
    for (int r = 0; r < BG; r++){ float zr = z[r] + bb; s += zr; q += zr*zr; }
    float mean = s*(1.f/BG), var = q*(1.f/BG) - mean*mean;
    float inv = rsqrtf(var + BNEPS);
    float gg = gf2[c], b2 = bef2[c];
    #pragma unroll
    for (int r = 0; r < BG; r++)
      s2g[r*256 + c] = fmaxf(gg*(z[r] + bb - mean)*inv + b2, 0.f);
  }
}

// ---- head fc3 + log_softmax ----
__global__ void k_fc3(const float* s2g, const float* wf3, const float* bf3, float* out){
  __shared__ float s2[BG*256];
  __shared__ float sl[BG*NCL];
  int t = threadIdx.x;
  for (int i = t; i < BG*256; i += 256) s2[i] = s2g[i];
  __syncthreads();
  if (t < BG*NCL){
    int r = t / NCL, c = t - r*NCL;
    float s = bf3[c];
    for (int k = 0; k < 256; k++) s += s2[r*256 + k]*wf3[k*NCL + c];
    sl[t] = s;
  }
  __syncthreads();
  if (t < BG){
    float m = -1e30f;
    for (int c = 0; c < NCL; c++) m = fmaxf(m, sl[t*NCL + c]);
    float s = 0.f;
    for (int c = 0; c < NCL; c++) s += expf(sl[t*NCL + c] - m);
    float lg = logf(s) + m;
    for (int c = 0; c < NCL; c++) out[t*NCL + c] = sl[t*NCL + c] - lg;
  }
}

extern "C" void kernel_launch(void* const* d_in, const int* in_sizes, int n_in,
                              void* d_out, int out_size, void* d_ws, size_t ws_size,
                              hipStream_t stream){
  const float* x    = (const float*)d_in[0];
  const float* ea   = (const float*)d_in[1];
  const float* we   = (const float*)d_in[2];
  const float* bedg = (const float*)d_in[3];
  const float* w1   = (const float*)d_in[4];  const float* b1  = (const float*)d_in[5];
  const float* g1   = (const float*)d_in[6];  const float* be1 = (const float*)d_in[7];
  const float* w2   = (const float*)d_in[8];  const float* b2  = (const float*)d_in[9];
  const float* g2   = (const float*)d_in[10]; const float* be2 = (const float*)d_in[11];
  const float* w3   = (const float*)d_in[12]; const float* b3  = (const float*)d_in[13];
  const float* g3   = (const float*)d_in[14]; const float* be3 = (const float*)d_in[15];
  const float* wf1  = (const float*)d_in[16]; const float* bf1 = (const float*)d_in[17];
  const float* gf1  = (const float*)d_in[18]; const float* bef1= (const float*)d_in[19];
  const float* wf2  = (const float*)d_in[20]; const float* bf2 = (const float*)d_in[21];
  const float* gf2  = (const float*)d_in[22]; const float* bef2= (const float*)d_in[23];
  const float* wf3  = (const float*)d_in[24]; const float* bf3 = (const float*)d_in[25];
  const void* ei    = d_in[26];
  const void* batch = d_in[27];
  float* out = (float*)d_out;

  float* ws = (float*)d_ws;
  float* deg   = ws; ws += NN;
  float* dis   = ws; ws += NN;
  float* csr_w = ws; ws += EEPAD;
  float* P1    = ws; ws += NN*FH1;
  float* P2    = ws; ws += NN*FH2;
  float* P3    = ws; ws += NN*FH2;
  float* csp1  = ws; ws += NBANK*128;
  float* csp2  = ws; ws += NBANK*128;
  float* csp3  = ws; ws += NBANK*128;
  float* embf  = ws; ws += BG*64;
  float* s1g   = ws; ws += BG*512;
  float* s2g   = ws; ws += BG*256;
  int* wi = (int*)ws;
  int* cnt    = wi; wi += NN;
  int* rowptr = wi; wi += NN;
  int* fillp  = wi; wi += NN;
  int* bsum   = wi; wi += 64;
  int* flags  = wi; wi += 2;
  uintptr_t ap = ((uintptr_t)wi + 15) & ~(uintptr_t)15;
  u16* csr_col = (u16*)ap;

  k_pre<<<48, 256, 0, stream>>>(deg, cnt, csp1, csp2, csp3, ei, batch, flags);
  k_edge<<<cdiv(EE,256), 256, 0, stream>>>(ea, we, bedg, ei, flags, deg, cnt);
  k_scanA<<<48, 256, 0, stream>>>(cnt, rowptr, bsum);
  k_scanB<<<48, 256, 0, stream>>>(bsum, deg, cnt, rowptr, fillp, dis, csr_col, csr_w);
  k_fill<<<cdiv(EE,256), 256, 0, stream>>>(ea, we, bedg, ei, flags, dis, fillp, csr_col, csr_w);

  // layer 1: x(15) -> P1(32)
  k_layer<FIN,16,FH1,0><<<NN/16, 256, 0, stream>>>(x, nullptr, nullptr, nullptr,
      w1, b1, rowptr, cnt, csr_col, csr_w, dis, P1, csp1);
  // layer 2: BN1(P1)(32) -> P2(64)
  k_layer<FH1,32,FH2,1><<<NN/8, 256, 0, stream>>>(P1, csp1, g1, be1,
      w2, b2, rowptr, cnt, csr_col, csr_w, dis, P2, csp2);
  // layer 3: BN2(P2)(64) -> P3(64)
  k_layer<FH2,64,FH2,1><<<NN/4, 256, 0, stream>>>(P2, csp2, g2, be2,
      w3, b3, rowptr, cnt, csr_col, csr_w, dis, P3, csp3);

  k_pool<<<BG, 256, 0, stream>>>(P3, csp3, g3, be3, batch, flags, embf, out);
  k_fcA<<<128, 256, 0, stream>>>(embf, wf1, bf1, gf1, bef1, s1g);
  k_fcB<<<64, 256, 0, stream>>>(s1g, wf2, bf2, gf2, bef2, s2g);
  k_fc3<<<1, 256, 0, stream>>>(s2g, wf3, bf3, out);
}

// Round 10
// 268.660 us; speedup vs baseline: 3.3641x; 1.1498x over previous
//
#include <hip/hip_runtime.h>
#include <hip/hip_bf16.h>

#define NN   12288
#define EE   393216
#define EEPAD (EE + 8*NN)
#define BG   16
#define FIN  15
#define FH1  32
#define FH2  64
#define NCL  11
#define BNEPS 1e-5f
#define NBANK 32

typedef unsigned short u16;
typedef unsigned long long u64;
static inline int cdiv(long a, long b){ return (int)((a + b - 1) / b); }

__device__ __forceinline__ int getIdx(const void* p, long i, int is64){
  return is64 ? (int)((const long long*)p)[i] : ((const int*)p)[i];
}

// ---- pre: init deg_cnt, zero colstat banks, detect int width ----
__global__ void k_pre(u64* deg_cnt, float* csp1, float* csp2, float* csp3,
                      const void* ei, const void* batch, int* flags){
  int g = blockIdx.x*256 + threadIdx.x;
  if (g < NN) deg_cnt[g] = 0ull;
  if (g < NBANK*128){ csp1[g] = 0.f; csp2[g] = 0.f; csp3[g] = 0.f; }
  if (blockIdx.x == 0 && threadIdx.x < 64){
    const int* a = (const int*)ei;
    unsigned long long m0 = __ballot(a[2*threadIdx.x + 1] == 0);
    const int* b = (const int*)batch;
    int j = 96*threadIdx.x;
    unsigned long long m1 = __ballot(b[2*j + 1] == 0);
    if (threadIdx.x == 0){
      flags[0] = (m0 == ~0ull) ? 1 : 0;
      flags[1] = (m1 == ~0ull) ? 1 : 0;
    }
  }
}

// ---- edge pass 1: ONE u64 atomic per edge.
// high32 = count, low32 = fixed-point (2^20) weighted degree.
// Return value's high32 = this edge's slot within its row.
__global__ void k_edge(const float* ea, const float* we, const float* bedg,
                       const void* ei, const int* flags, u64* deg_cnt, int* sslot){
  int e = blockIdx.x*256 + threadIdx.x;
  if (e >= EE) return;
  int is64 = flags[0];
  float z = ea[2*e]*we[0] + ea[2*e+1]*we[1] + bedg[0];
  float w = 1.0f/(1.0f + expf(-z));
  int r = getIdx(ei, e, is64);
  u64 add = (1ull << 32) | (u64)__float2uint_rn(w * 1048576.0f);
  u64 old = atomicAdd(&deg_cnt[r], add);
  sslot[e] = (int)(old >> 32);
}

// ---- scan A: per-block scan of PADDED counts -> rowptr (exclusive), bsum ----
__global__ void k_scanA(const u64* deg_cnt, int* rowptr, int* bsum){
  __shared__ int sbuf[256];
  int i = blockIdx.x*256 + threadIdx.x;
  int v = ((int)(deg_cnt[i] >> 32) + 7) & ~7;   // pad row to multiple of 8 slots
  sbuf[threadIdx.x] = v;
  __syncthreads();
  for (int off = 1; off < 256; off <<= 1){
    int add = (threadIdx.x >= off) ? sbuf[threadIdx.x - off] : 0;
    __syncthreads();
    sbuf[threadIdx.x] += add;
    __syncthreads();
  }
  rowptr[i] = sbuf[threadIdx.x] - v;
  if (threadIdx.x == 255) bsum[blockIdx.x] = sbuf[255];
}

// ---- scan B: apply block offsets; dis from fixed-point degree; zero pad slots ----
__global__ void k_scanB(const int* bsum, const u64* deg_cnt,
                        int* rowptr, float* dis, u64* csr_p){
  __shared__ int sbx[64];
  if (threadIdx.x < 64){
    int v = (threadIdx.x < 48) ? bsum[threadIdx.x] : 0;
    sbx[threadIdx.x] = v;
  }
  __syncthreads();
  for (int off = 1; off < 64; off <<= 1){
    int add = (threadIdx.x < 64 && threadIdx.x >= off) ? sbx[threadIdx.x - off] : 0;
    __syncthreads();
    if (threadIdx.x < 64) sbx[threadIdx.x] += add;
    __syncthreads();
  }
  __syncthreads();
  int off = (blockIdx.x == 0) ? 0 : sbx[blockIdx.x - 1];
  int i = blockIdx.x*256 + threadIdx.x;
  int rp = rowptr[i] + off;
  rowptr[i] = rp;
  u64 dc = deg_cnt[i];
  float deg = 1.0f + (float)(unsigned)(dc & 0xffffffffull) * (1.0f/1048576.0f);
  dis[i] = rsqrtf(deg);
  int n = (int)(dc >> 32), np = (n + 7) & ~7;
  for (int s = rp + n; s < rp + np; s++) csr_p[s] = 0ull;  // w=+0, col=0
}

// ---- edge pass 2: NO atomics — slot was captured in pass 1 ----
__global__ void k_fill(const float* ea, const float* we, const float* bedg,
                       const void* ei, const int* flags, const float* dis,
                       const int* rowptr, const int* sslot, u64* csr_p){
  int e = blockIdx.x*256 + threadIdx.x;
  if (e >= EE) return;
  int is64 = flags[0];
  int r = getIdx(ei, e, is64);
  int c = getIdx(ei, (long)EE + e, is64);
  float z = ea[2*e]*we[0] + ea[2*e+1]*we[1] + bedg[0];
  float w = 1.0f/(1.0f + expf(-z));
  float wv = w * dis[c];
  int slot = rowptr[r] + sslot[e];
  csr_p[slot] = (u64)(unsigned)c | ((u64)__float_as_uint(wv) << 32);
}

// ---- fused GCN layer, one tile per block ----
// packed CSR chunks of 8: 4 independent uint4 loads + prefetch of next chunk
template<int F, int FP, int FO, int APPLY_BN>
__global__ void __launch_bounds__(256) k_layer(
    const float* __restrict__ Hin, const float* __restrict__ csin,
    const float* __restrict__ g, const float* __restrict__ be,
    const float* __restrict__ W, const float* __restrict__ bias,
    const int* __restrict__ rowptr, const u64* __restrict__ deg_cnt,
    const u64* __restrict__ csr_p, const float* __restrict__ dis,
    float* __restrict__ Pout, float* __restrict__ csout){
  const int R = 256/FP;
  __shared__ float At[R][FP];
  __shared__ float lcs[FO], lcq[FO];
  if (threadIdx.x < FO){ lcs[threadIdx.x] = 0.f; lcq[threadIdx.x] = 0.f; }
  int f = threadIdx.x % FP, lr = threadIdx.x / FP;
  float sc = 1.f, sh = 0.f;
  if (APPLY_BN && f < F){
    float s = 0.f, q = 0.f;
    #pragma unroll
    for (int b = 0; b < NBANK; b++){ s += csin[b*128 + f]; q += csin[b*128 + 64 + f]; }
    float mu  = s*(1.0f/NN);
    float var = q*(1.0f/NN) - mu*mu;
    float rinv = rsqrtf(var + BNEPS);
    sc = g[f]*rinv; sh = be[f] - mu*sc;
  }
  int row = blockIdx.x*R + lr;
  if (f < F){
    float d = dis[row];
    float v0 = Hin[row*F + f];
    if (APPLY_BN) v0 = fmaxf(v0*sc + sh, 0.f);
    float acc = d * v0;                       // self loop
    int beg = rowptr[row];
    int n = (int)(deg_cnt[row] >> 32);
    int nch = (n + 7) >> 3;
    const uint4* pb = (const uint4*)(csr_p + beg);
    if (nch > 0){
      uint4 a0 = pb[0], a1 = pb[1], a2 = pb[2], a3 = pb[3];
      for (int ch = 0; ch < nch; ch++){
        uint4 b0, b1, b2, b3;
        bool more = (ch + 1 < nch);
        if (more){ b0 = pb[4*ch+4]; b1 = pb[4*ch+5]; b2 = pb[4*ch+6]; b3 = pb[4*ch+7]; }
        float h0 = Hin[(int)a0.x*F + f];
        float h1 = Hin[(int)a0.z*F + f];
        float h2 = Hin[(int)a1.x*F + f];
        float h3 = Hin[(int)a1.z*F + f];
        float h4 = Hin[(int)a2.x*F + f];
        float h5 = Hin[(int)a2.z*F + f];
        float h6 = Hin[(int)a3.x*F + f];
        float h7 = Hin[(int)a3.z*F + f];
        if (APPLY_BN){
          h0 = fmaxf(h0*sc + sh, 0.f); h1 = fmaxf(h1*sc + sh, 0.f);
          h2 = fmaxf(h2*sc + sh, 0.f); h3 = fmaxf(h3*sc + sh, 0.f);
          h4 = fmaxf(h4*sc + sh, 0.f); h5 = fmaxf(h5*sc + sh, 0.f);
          h6 = fmaxf(h6*sc + sh, 0.f); h7 = fmaxf(h7*sc + sh, 0.f);
        }
        acc += __uint_as_float(a0.y)*h0 + __uint_as_float(a0.w)*h1
             + __uint_as_float(a1.y)*h2 + __uint_as_float(a1.w)*h3
             + __uint_as_float(a2.y)*h4 + __uint_as_float(a2.w)*h5
             + __uint_as_float(a3.y)*h6 + __uint_as_float(a3.w)*h7;
        if (more){ a0 = b0; a1 = b1; a2 = b2; a3 = b3; }
      }
    }
    At[lr][f] = d * acc;
  }
  __syncthreads();
  const int fo = threadIdx.x % FO;     // 256 % FO == 0
  float bb = bias[fo];
  for (int o = threadIdx.x; o < R*FO; o += 256){
    int l = o / FO;
    float s = bb;
    #pragma unroll
    for (int fi = 0; fi < F; fi++) s += At[l][fi] * W[fi*FO + fo];
    Pout[(blockIdx.x*R + l)*FO + fo] = s;
    atomicAdd(&lcs[fo], s);
    atomicAdd(&lcq[fo], s*s);
  }
  __syncthreads();
  if (threadIdx.x < FO){
    int bank = blockIdx.x & (NBANK-1);
    atomicAdd(&csout[bank*128 + threadIdx.x],      lcs[threadIdx.x]);
    atomicAdd(&csout[bank*128 + 64 + threadIdx.x], lcq[threadIdx.x]);
  }
}

// ---- pool: BN3 on load, per-graph max, write embf + emb part of out ----
__global__ void k_pool(const float* P3, const float* cs3, const float* g3,
                       const float* be3, const void* batch, const int* flags,
                       float* embf, float* out){
  int is64 = flags[1];
  int b = blockIdx.x;
  int lo = 0, hi = NN;
  while (lo < hi){ int m = (lo+hi)>>1; if (getIdx(batch, m, is64) < b) lo = m+1; else hi = m; }
  int start = lo;
  lo = start; hi = NN;
  while (lo < hi){ int m = (lo+hi)>>1; if (getIdx(batch, m, is64) < b+1) lo = m+1; else hi = m; }
  int end = lo;
  int f = threadIdx.x & 63, grp = threadIdx.x >> 6;
  float s = 0.f, q = 0.f;
  #pragma unroll
  for (int bk = 0; bk < NBANK; bk++){ s += cs3[bk*128 + f]; q += cs3[bk*128 + 64 + f]; }
  float mu  = s*(1.0f/NN);
  float var = q*(1.0f/NN) - mu*mu;
  float rinv = rsqrtf(var + BNEPS);
  float sc = g3[f]*rinv, sh = be3[f] - mu*sc;
  float m = 0.0f;
  for (int i = start + grp; i < end; i += 4)
    m = fmaxf(m, P3[(long)i*FH2 + f]*sc + sh);
  __shared__ float shm[4][64];
  shm[grp][f] = m;
  __syncthreads();
  if (grp == 0){
    float v = fmaxf(fmaxf(shm[0][f], shm[1][f]), fmaxf(shm[2][f], shm[3][f]));
    embf[b*64 + f] = v;
    out[BG*NCL + b*64 + f] = v;
  }
}

// ---- head fc1 + BN + relu: wave per column ----
__global__ void __launch_bounds__(256) k_fcA(const float* embf, const float* wf1,
    const float* bf1, const float* gf1, const float* bef1, float* s1g){
  int c = blockIdx.x*4 + (threadIdx.x >> 6);
  int l = threadIdx.x & 63;
  float wcol = wf1[l*512 + c];
  float z[BG];
  #pragma unroll
  for (int r = 0; r < BG; r++){
    float v = embf[r*64 + l] * wcol;
    #pragma unroll
    for (int off = 32; off > 0; off >>= 1) v += __shfl_down(v, off);
    z[r] = v;                 // valid on lane 0
  }
  if (l == 0){
    float bb = bf1[c];
    float s = 0.f, q = 0.f;
    #pragma unroll
    for (int r = 0; r < BG; r++){ float zr = z[r] + bb; s += zr; q += zr*zr; }
    float mean = s*(1.f/BG), var = q*(1.f/BG) - mean*mean;
    float inv = rsqrtf(var + BNEPS);
    float gg = gf1[c], b2 = bef1[c];
    #pragma unroll
    for (int r = 0; r < BG; r++)
      s1g[r*512 + c] = fmaxf(gg*(z[r] + bb - mean)*inv + b2, 0.f);
  }
}

// ---- head fc2 + BN + relu: wave per column ----
__global__ void __launch_bounds__(256) k_fcB(const float* s1g, const float* wf2,
    const float* bf2, const float* gf2, const float* bef2, float* s2g){
  int c = blockIdx.x*4 + (threadIdx.x >> 6);
  int l = threadIdx.x & 63;
  float wreg[8];
  #pragma unroll
  for (int j = 0; j < 8; j++) wreg[j] = wf2[(l + 64*j)*256 + c];
  float z[BG];
  #pragma unroll
  for (int r = 0; r < BG; r++){
    float v = 0.f;
    #pragma unroll
    for (int j = 0; j < 8; j++) v += s1g[r*512 + l + 64*j] * wreg[j];
    #pragma unroll
    for (int off = 32; off > 0; off >>= 1) v += __shfl_down(v, off);
    z[r] = v;
  }
  if (l == 0){
    float bb = bf2[c];
    float s = 0.f, q = 0.f;
    #pragma unroll
    for (int r = 0; r < BG; r++){ float zr = z[r] + bb; s += zr; q += zr*zr; }
    float mean = s*(1.f/BG), var = q*(1.f/BG) - mean*mean;
    float inv = rsqrtf(var + BNEPS);
    float gg = gf2[c], b2 = bef2[c];
    #pragma unroll
    for (int r = 0; r < BG; r++)
      s2g[r*256 + c] = fmaxf(gg*(z[r] + bb - mean)*inv + b2, 0.f);
  }
}

// ---- head fc3 + log_softmax ----
__global__ void k_fc3(const float* s2g, const float* wf3, const float* bf3, float* out){
  __shared__ float s2[BG*256];
  __shared__ float sl[BG*NCL];
  int t = threadIdx.x;
  for (int i = t; i < BG*256; i += 256) s2[i] = s2g[i];
  __syncthreads();
  if (t < BG*NCL){
    int r = t / NCL, c = t - r*NCL;
    float s = bf3[c];
    for (int k = 0; k < 256; k++) s += s2[r*256 + k]*wf3[k*NCL + c];
    sl[t] = s;
  }
  __syncthreads();
  if (t < BG){
    float m = -1e30f;
    for (int c = 0; c < NCL; c++) m = fmaxf(m, sl[t*NCL + c]);
    float s = 0.f;
    for (int c = 0; c < NCL; c++) s += expf(sl[t*NCL + c] - m);
    float lg = logf(s) + m;
    for (int c = 0; c < NCL; c++) out[t*NCL + c] = sl[t*NCL + c] - lg;
  }
}

extern "C" void kernel_launch(void* const* d_in, const int* in_sizes, int n_in,
                              void* d_out, int out_size, void* d_ws, size_t ws_size,
                              hipStream_t stream){
  const float* x    = (const float*)d_in[0];
  const float* ea   = (const float*)d_in[1];
  const float* we   = (const float*)d_in[2];
  const float* bedg = (const float*)d_in[3];
  const float* w1   = (const float*)d_in[4];  const float* b1  = (const float*)d_in[5];
  const float* g1   = (const float*)d_in[6];  const float* be1 = (const float*)d_in[7];
  const float* w2   = (const float*)d_in[8];  const float* b2  = (const float*)d_in[9];
  const float* g2   = (const float*)d_in[10]; const float* be2 = (const float*)d_in[11];
  const float* w3   = (const float*)d_in[12]; const float* b3  = (const float*)d_in[13];
  const float* g3   = (const float*)d_in[14]; const float* be3 = (const float*)d_in[15];
  const float* wf1  = (const float*)d_in[16]; const float* bf1 = (const float*)d_in[17];
  const float* gf1  = (const float*)d_in[18]; const float* bef1= (const float*)d_in[19];
  const float* wf2  = (const float*)d_in[20]; const float* bf2 = (const float*)d_in[21];
  const float* gf2  = (const float*)d_in[22]; const float* bef2= (const float*)d_in[23];
  const float* wf3  = (const float*)d_in[24]; const float* bf3 = (const float*)d_in[25];
  const void* ei    = d_in[26];
  const void* batch = d_in[27];
  float* out = (float*)d_out;

  // u64 arrays first (8B alignment off the base pointer)
  u64* wq = (u64*)d_ws;
  u64* deg_cnt = wq; wq += NN;
  u64* csr_p   = wq; wq += EEPAD;
  float* ws = (float*)wq;
  float* dis   = ws; ws += NN;
  float* P1    = ws; ws += NN*FH1;
  float* P2    = ws; ws += NN*FH2;
  float* P3    = ws; ws += NN*FH2;
  float* csp1  = ws; ws += NBANK*128;
  float* csp2  = ws; ws += NBANK*128;
  float* csp3  = ws; ws += NBANK*128;
  float* embf  = ws; ws += BG*64;
  float* s1g   = ws; ws += BG*512;
  float* s2g   = ws; ws += BG*256;
  int* wi = (int*)ws;
  int* rowptr = wi; wi += NN;
  int* sslot  = wi; wi += EE;
  int* bsum   = wi; wi += 64;
  int* flags  = wi; wi += 2;

  k_pre<<<48, 256, 0, stream>>>(deg_cnt, csp1, csp2, csp3, ei, batch, flags);
  k_edge<<<cdiv(EE,256), 256, 0, stream>>>(ea, we, bedg, ei, flags, deg_cnt, sslot);
  k_scanA<<<48, 256, 0, stream>>>(deg_cnt, rowptr, bsum);
  k_scanB<<<48, 256, 0, stream>>>(bsum, deg_cnt, rowptr, dis, csr_p);
  k_fill<<<cdiv(EE,256), 256, 0, stream>>>(ea, we, bedg, ei, flags, dis, rowptr, sslot, csr_p);

  // layer 1: x(15) -> P1(32)
  k_layer<FIN,16,FH1,0><<<NN/16, 256, 0, stream>>>(x, nullptr, nullptr, nullptr,
      w1, b1, rowptr, deg_cnt, csr_p, dis, P1, csp1);
  // layer 2: BN1(P1)(32) -> P2(64)
  k_layer<FH1,32,FH2,1><<<NN/8, 256, 0, stream>>>(P1, csp1, g1, be1,
      w2, b2, rowptr, deg_cnt, csr_p, dis, P2, csp2);
  // layer 3: BN2(P2)(64) -> P3(64)
  k_layer<FH2,64,FH2,1><<<NN/4, 256, 0, stream>>>(P2, csp2, g2, be2,
      w3, b3, rowptr, deg_cnt, csr_p, dis, P3, csp3);

  k_pool<<<BG, 256, 0, stream>>>(P3, csp3, g3, be3, batch, flags, embf, out);
  k_fcA<<<128, 256, 0, stream>>>(embf, wf1, bf1, gf1, bef1, s1g);
  k_fcB<<<64, 256, 0, stream>>>(s1g, wf2, bf2, gf2, bef2, s2g);
  k_fc3<<<1, 256, 0, stream>>>(s2g, wf3, bf3, out);
}

// Round 11
// 265.704 us; speedup vs baseline: 3.4015x; 1.0111x over previous
//
#include <hip/hip_runtime.h>
#include <hip/hip_bf16.h>

#define NN   12288
#define EE   393216
#define WELL 96                 // ELL slots per row (max degree ~64 + margin)
#define NELL (NN*WELL)
#define BG   16
#define FIN  15
#define FH1  32
#define FH2  64
#define NCL  11
#define BNEPS 1e-5f
#define NBANK 32

typedef unsigned long long u64;
static inline int cdiv(long a, long b){ return (int)((a + b - 1) / b); }

__device__ __forceinline__ int getIdx(const void* p, long i, int is64){
  return is64 ? (int)((const long long*)p)[i] : ((const int*)p)[i];
}

__device__ __forceinline__ float degOf(u64 dc){
  return 1.0f + (float)(unsigned)(dc & 0xffffffffull) * (1.0f/1048576.0f);
}

// ---- pre: zero ELL (9.4 MB) + deg_cnt + colstat banks; detect int width ----
__global__ void k_pre(u64* deg_cnt, uint4* csr_q, float* csp1, float* csp2,
                      float* csp3, const void* ei, const void* batch, int* flags){
  int g = blockIdx.x*256 + threadIdx.x;
  if (g < NELL/2) csr_q[g] = make_uint4(0,0,0,0);   // 2 slots per uint4
  if (g < NN) deg_cnt[g] = 0ull;
  if (g < NBANK*128){ csp1[g] = 0.f; csp2[g] = 0.f; csp3[g] = 0.f; }
  if (blockIdx.x == 0 && threadIdx.x < 64){
    const int* a = (const int*)ei;
    unsigned long long m0 = __ballot(a[2*threadIdx.x + 1] == 0);
    const int* b = (const int*)batch;
    int j = 96*threadIdx.x;
    unsigned long long m1 = __ballot(b[2*j + 1] == 0);
    if (threadIdx.x == 0){
      flags[0] = (m0 == ~0ull) ? 1 : 0;
      flags[1] = (m1 == ~0ull) ? 1 : 0;
    }
  }
}

// ---- edge pass: ONE u64 atomic per edge; returned count = ELL slot.
// Writes packed (col, sigmoid-w) directly; dis applied later by k_fix.
__global__ void k_edge(const float* ea, const float* we, const float* bedg,
                       const void* ei, const int* flags, u64* deg_cnt, u64* csr_p){
  int e = blockIdx.x*256 + threadIdx.x;
  if (e >= EE) return;
  int is64 = flags[0];
  float z = ea[2*e]*we[0] + ea[2*e+1]*we[1] + bedg[0];
  float w = 1.0f/(1.0f + expf(-z));
  int r = getIdx(ei, e, is64);
  int c = getIdx(ei, (long)EE + e, is64);
  u64 add = (1ull << 32) | (u64)__float2uint_rn(w * 1048576.0f);
  u64 old = atomicAdd(&deg_cnt[r], add);
  int slot = (int)(old >> 32);
  if (slot < WELL)
    csr_p[r*WELL + slot] = (u64)(unsigned)c | ((u64)__float_as_uint(w) << 32);
}

// ---- fix pass: w *= rsqrt(deg[col]) for every real slot (coalesced) ----
__global__ void k_fix(u64* csr_p, const u64* deg_cnt){
  int g = blockIdx.x*256 + threadIdx.x;
  if (g >= NELL) return;
  u64 v = csr_p[g];
  unsigned wu = (unsigned)(v >> 32);
  if (wu == 0u) return;                       // pad slot
  int c = (int)(unsigned)(v & 0xffffffffull);
  float w = __uint_as_float(wu) * rsqrtf(degOf(deg_cnt[c]));
  ((unsigned*)csr_p)[2*g + 1] = __float_as_uint(w);
}

// ---- fused GCN layer, one tile per block, ELL chunks of 8 + prefetch ----
template<int F, int FP, int FO, int APPLY_BN>
__global__ void __launch_bounds__(256) k_layer(
    const float* __restrict__ Hin, const float* __restrict__ csin,
    const float* __restrict__ g, const float* __restrict__ be,
    const float* __restrict__ W, const float* __restrict__ bias,
    const u64* __restrict__ deg_cnt, const u64* __restrict__ csr_p,
    float* __restrict__ Pout, float* __restrict__ csout){
  const int R = 256/FP;
  __shared__ float At[R][FP];
  __shared__ float lcs[FO], lcq[FO];
  if (threadIdx.x < FO){ lcs[threadIdx.x] = 0.f; lcq[threadIdx.x] = 0.f; }
  int f = threadIdx.x % FP, lr = threadIdx.x / FP;
  float sc = 1.f, sh = 0.f;
  if (APPLY_BN && f < F){
    float s = 0.f, q = 0.f;
    #pragma unroll
    for (int b = 0; b < NBANK; b++){ s += csin[b*128 + f]; q += csin[b*128 + 64 + f]; }
    float mu  = s*(1.0f/NN);
    float var = q*(1.0f/NN) - mu*mu;
    float rinv = rsqrtf(var + BNEPS);
    sc = g[f]*rinv; sh = be[f] - mu*sc;
  }
  int row = blockIdx.x*R + lr;
  if (f < F){
    u64 dc = deg_cnt[row];
    float d = rsqrtf(degOf(dc));
    int n = (int)(dc >> 32);
    float v0 = Hin[row*F + f];
    if (APPLY_BN) v0 = fmaxf(v0*sc + sh, 0.f);
    float acc = d * v0;                       // self loop
    int nch = (n + 7) >> 3;
    const uint4* pb = (const uint4*)(csr_p + row*WELL);
    if (nch > 0){
      uint4 a0 = pb[0], a1 = pb[1], a2 = pb[2], a3 = pb[3];
      for (int ch = 0; ch < nch; ch++){
        uint4 b0, b1, b2, b3;
        bool more = (ch + 1 < nch);
        if (more){ b0 = pb[4*ch+4]; b1 = pb[4*ch+5]; b2 = pb[4*ch+6]; b3 = pb[4*ch+7]; }
        float h0 = Hin[(int)a0.x*F + f];
        float h1 = Hin[(int)a0.z*F + f];
        float h2 = Hin[(int)a1.x*F + f];
        float h3 = Hin[(int)a1.z*F + f];
        float h4 = Hin[(int)a2.x*F + f];
        float h5 = Hin[(int)a2.z*F + f];
        float h6 = Hin[(int)a3.x*F + f];
        float h7 = Hin[(int)a3.z*F + f];
        if (APPLY_BN){
          h0 = fmaxf(h0*sc + sh, 0.f); h1 = fmaxf(h1*sc + sh, 0.f);
          h2 = fmaxf(h2*sc + sh, 0.f); h3 = fmaxf(h3*sc + sh, 0.f);
          h4 = fmaxf(h4*sc + sh, 0.f); h5 = fmaxf(h5*sc + sh, 0.f);
          h6 = fmaxf(h6*sc + sh, 0.f); h7 = fmaxf(h7*sc + sh, 0.f);
        }
        acc += __uint_as_float(a0.y)*h0 + __uint_as_float(a0.w)*h1
             + __uint_as_float(a1.y)*h2 + __uint_as_float(a1.w)*h3
             + __uint_as_float(a2.y)*h4 + __uint_as_float(a2.w)*h5
             + __uint_as_float(a3.y)*h6 + __uint_as_float(a3.w)*h7;
        if (more){ a0 = b0; a1 = b1; a2 = b2; a3 = b3; }
      }
    }
    At[lr][f] = d * acc;
  }
  __syncthreads();
  const int fo = threadIdx.x % FO;     // 256 % FO == 0
  float bb = bias[fo];
  for (int o = threadIdx.x; o < R*FO; o += 256){
    int l = o / FO;
    float s = bb;
    #pragma unroll
    for (int fi = 0; fi < F; fi++) s += At[l][fi] * W[fi*FO + fo];
    Pout[(blockIdx.x*R + l)*FO + fo] = s;
    atomicAdd(&lcs[fo], s);
    atomicAdd(&lcq[fo], s*s);
  }
  __syncthreads();
  if (threadIdx.x < FO){
    int bank = blockIdx.x & (NBANK-1);
    atomicAdd(&csout[bank*128 + threadIdx.x],      lcs[threadIdx.x]);
    atomicAdd(&csout[bank*128 + 64 + threadIdx.x], lcq[threadIdx.x]);
  }
}

// ---- pool: BN3 on load, per-graph max, write embf + emb part of out ----
__global__ void k_pool(const float* P3, const float* cs3, const float* g3,
                       const float* be3, const void* batch, const int* flags,
                       float* embf, float* out){
  int is64 = flags[1];
  int b = blockIdx.x;
  int lo = 0, hi = NN;
  while (lo < hi){ int m = (lo+hi)>>1; if (getIdx(batch, m, is64) < b) lo = m+1; else hi = m; }
  int start = lo;
  lo = start; hi = NN;
  while (lo < hi){ int m = (lo+hi)>>1; if (getIdx(batch, m, is64) < b+1) lo = m+1; else hi = m; }
  int end = lo;
  int f = threadIdx.x & 63, grp = threadIdx.x >> 6;
  float s = 0.f, q = 0.f;
  #pragma unroll
  for (int bk = 0; bk < NBANK; bk++){ s += cs3[bk*128 + f]; q += cs3[bk*128 + 64 + f]; }
  float mu  = s*(1.0f/NN);
  float var = q*(1.0f/NN) - mu*mu;
  float rinv = rsqrtf(var + BNEPS);
  float sc = g3[f]*rinv, sh = be3[f] - mu*sc;
  float m = 0.0f;
  for (int i = start + grp; i < end; i += 4)
    m = fmaxf(m, P3[(long)i*FH2 + f]*sc + sh);
  __shared__ float shm[4][64];
  shm[grp][f] = m;
  __syncthreads();
  if (grp == 0){
    float v = fmaxf(fmaxf(shm[0][f], shm[1][f]), fmaxf(shm[2][f], shm[3][f]));
    embf[b*64 + f] = v;
    out[BG*NCL + b*64 + f] = v;
  }
}

// ---- head fc1 + BN + relu: wave per column ----
__global__ void __launch_bounds__(256) k_fcA(const float* embf, const float* wf1,
    const float* bf1, const float* gf1, const float* bef1, float* s1g){
  int c = blockIdx.x*4 + (threadIdx.x >> 6);
  int l = threadIdx.x & 63;
  float wcol = wf1[l*512 + c];
  float z[BG];
  #pragma unroll
  for (int r = 0; r < BG; r++){
    float v = embf[r*64 + l] * wcol;
    #pragma unroll
    for (int off = 32; off > 0; off >>= 1) v += __shfl_down(v, off);
    z[r] = v;                 // valid on lane 0
  }
  if (l == 0){
    float bb = bf1[c];
    float s = 0.f, q = 0.f;
    #pragma unroll
    for (int r = 0; r < BG; r++){ float zr = z[r] + bb; s += zr; q += zr*zr; }
    float mean = s*(1.f/BG), var = q*(1.f/BG) - mean*mean;
    float inv = rsqrtf(var + BNEPS);
    float gg = gf1[c], b2 = bef1[c];
    #pragma unroll
    for (int r = 0; r < BG; r++)
      s1g[r*512 + c] = fmaxf(gg*(z[r] + bb - mean)*inv + b2, 0.f);
  }
}

// ---- head fc2 + BN + relu: wave per column ----
__global__ void __launch_bounds__(256) k_fcB(const float* s1g, const float* wf2,
    const float* bf2, const float* gf2, const float* bef2, float* s2g){
  int c = blockIdx.x*4 + (threadIdx.x >> 6);
  int l = threadIdx.x & 63;
  float wreg[8];
  #pragma unroll
  for (int j = 0; j < 8; j++) wreg[j] = wf2[(l + 64*j)*256 + c];
  float z[BG];
  #pragma unroll
  for (int r = 0; r < BG; r++){
    float v = 0.f;
    #pragma unroll
    for (int j = 0; j < 8; j++) v += s1g[r*512 + l + 64*j] * wreg[j];
    #pragma unroll
    for (int off = 32; off > 0; off >>= 1) v += __shfl_down(v, off);
    z[r] = v;
  }
  if (l == 0){
    float bb = bf2[c];
    float s = 0.f, q = 0.f;
    #pragma unroll
    for (int r = 0; r < BG; r++){ float zr = z[r] + bb; s += zr; q += zr*zr; }
    float mean = s*(1.f/BG), var = q*(1.f/BG) - mean*mean;
    float inv = rsqrtf(var + BNEPS);
    float gg = gf2[c], b2 = bef2[c];
    #pragma unroll
    for (int r = 0; r < BG; r++)
      s2g[r*256 + c] = fmaxf(gg*(z[r] + bb - mean)*inv + b2, 0.f);
  }
}

// ---- head fc3 + log_softmax ----
__global__ void k_fc3(const float* s2g, const float* wf3, const float* bf3, float* out){
  __shared__ float s2[BG*256];
  __shared__ float sl[BG*NCL];
  int t = threadIdx.x;
  for (int i = t; i < BG*256; i += 256) s2[i] = s2g[i];
  __syncthreads();
  if (t < BG*NCL){
    int r = t / NCL, c = t - r*NCL;
    float s = bf3[c];
    for (int k = 0; k < 256; k++) s += s2[r*256 + k]*wf3[k*NCL + c];
    sl[t] = s;
  }
  __syncthreads();
  if (t < BG){
    float m = -1e30f;
    for (int c = 0; c < NCL; c++) m = fmaxf(m, sl[t*NCL + c]);
    float s = 0.f;
    for (int c = 0; c < NCL; c++) s += expf(sl[t*NCL + c] - m);
    float lg = logf(s) + m;
    for (int c = 0; c < NCL; c++) out[t*NCL + c] = sl[t*NCL + c] - lg;
  }
}

extern "C" void kernel_launch(void* const* d_in, const int* in_sizes, int n_in,
                              void* d_out, int out_size, void* d_ws, size_t ws_size,
                              hipStream_t stream){
  const float* x    = (const float*)d_in[0];
  const float* ea   = (const float*)d_in[1];
  const float* we   = (const float*)d_in[2];
  const float* bedg = (const float*)d_in[3];
  const float* w1   = (const float*)d_in[4];  const float* b1  = (const float*)d_in[5];
  const float* g1   = (const float*)d_in[6];  const float* be1 = (const float*)d_in[7];
  const float* w2   = (const float*)d_in[8];  const float* b2  = (const float*)d_in[9];
  const float* g2   = (const float*)d_in[10]; const float* be2 = (const float*)d_in[11];
  const float* w3   = (const float*)d_in[12]; const float* b3  = (const float*)d_in[13];
  const float* g3   = (const float*)d_in[14]; const float* be3 = (const float*)d_in[15];
  const float* wf1  = (const float*)d_in[16]; const float* bf1 = (const float*)d_in[17];
  const float* gf1  = (const float*)d_in[18]; const float* bef1= (const float*)d_in[19];
  const float* wf2  = (const float*)d_in[20]; const float* bf2 = (const float*)d_in[21];
  const float* gf2  = (const float*)d_in[22]; const float* bef2= (const float*)d_in[23];
  const float* wf3  = (const float*)d_in[24]; const float* bf3 = (const float*)d_in[25];
  const void* ei    = d_in[26];
  const void* batch = d_in[27];
  float* out = (float*)d_out;

  // u64 arrays first (alignment off the 256B-aligned base)
  u64* wq = (u64*)d_ws;
  u64* deg_cnt = wq; wq += NN;
  u64* csr_p   = wq; wq += NELL;
  float* ws = (float*)wq;
  float* P1    = ws; ws += NN*FH1;
  float* P2    = ws; ws += NN*FH2;
  float* P3    = ws; ws += NN*FH2;
  float* csp1  = ws; ws += NBANK*128;
  float* csp2  = ws; ws += NBANK*128;
  float* csp3  = ws; ws += NBANK*128;
  float* embf  = ws; ws += BG*64;
  float* s1g   = ws; ws += BG*512;
  float* s2g   = ws; ws += BG*256;
  int* flags   = (int*)ws;

  k_pre<<<cdiv(NELL/2,256), 256, 0, stream>>>(deg_cnt, (uint4*)csr_p,
                                              csp1, csp2, csp3, ei, batch, flags);
  k_edge<<<cdiv(EE,256), 256, 0, stream>>>(ea, we, bedg, ei, flags, deg_cnt, csr_p);
  k_fix<<<cdiv(NELL,256), 256, 0, stream>>>(csr_p, deg_cnt);

  // layer 1: x(15) -> P1(32)
  k_layer<FIN,16,FH1,0><<<NN/16, 256, 0, stream>>>(x, nullptr, nullptr, nullptr,
      w1, b1, deg_cnt, csr_p, P1, csp1);
  // layer 2: BN1(P1)(32) -> P2(64)
  k_layer<FH1,32,FH2,1><<<NN/8, 256, 0, stream>>>(P1, csp1, g1, be1,
      w2, b2, deg_cnt, csr_p, P2, csp2);
  // layer 3: BN2(P2)(64) -> P3(64)
  k_layer<FH2,64,FH2,1><<<NN/4, 256, 0, stream>>>(P2, csp2, g2, be2,
      w3, b3, deg_cnt, csr_p, P3, csp3);

  k_pool<<<BG, 256, 0, stream>>>(P3, csp3, g3, be3, batch, flags, embf, out);
  k_fcA<<<128, 256, 0, stream>>>(embf, wf1, bf1, gf1, bef1, s1g);
  k_fcB<<<64, 256, 0, stream>>>(s1g, wf2, bf2, gf2, bef2, s2g);
  k_fc3<<<1, 256, 0, stream>>>(s2g, wf3, bf3, out);
}